// Round 5
// baseline (169.250 us; speedup 1.0000x reference)
//
#include <hip/hip_runtime.h>

#define HWD 884736   // 96*96*96
#define KCLS 5
#define CCH 64
#define NC 4

constexpr int TPB = 256;
constexpr int VPT = 4;                     // voxels per worklist entry
constexpr int CHUNK = TPB * VPT;           // 1024 voxels per block
constexpr int NCHUNKS = 2 * HWD / CHUNK;   // 1728 (b never straddles a block)
constexpr int NPART = 16;
constexpr int PARTSZ = 272;                // 256 sums + 4 cnt @256 + 4 sq @260

__global__ __launch_bounds__(256) void pm_zero(float* __restrict__ part) {
    const int n = NPART * PARTSZ;
    for (int i = threadIdx.x; i < n; i += 256) part[i] = 0.f;
}

__global__ __launch_bounds__(TPB) void pm_pass1(
    const float* __restrict__ feat, const float* __restrict__ pred,
    const int* __restrict__ label, const unsigned char* __restrict__ is_lab,
    float* __restrict__ part)
{
    __shared__ int   wl[TPB];          // packed: srct<<12 | 4×3b (valid|class)
    __shared__ int   nwl;
    __shared__ float lcnt[NC];
    __shared__ float lsq[NC];
    __shared__ float lsum[NC][CCH];    // waves own disjoint channel columns

    const int t = threadIdx.x;
    const int w = t >> 6, lane = t & 63;
    if (t == 0) nwl = 0;
    if (t < NC) { lcnt[t] = 0.f; lsq[t] = 0.f; }
    ((float*)lsum)[t] = 0.f;           // NC*CCH == 256
    __syncthreads();

    const int chunk = blockIdx.x;
    const int b = (chunk >= NCHUNKS / 2) ? 1 : 0;     // HWD % CHUNK == 0
    const int s = chunk * CHUNK - b * HWD + t * VPT;

    // ---- phase 1: mask from pred/label (coalesced streams), build worklist ----
    {
        const float4* pb = (const float4*)(pred + (size_t)b * KCLS * HWD + s);
        float4 pk[KCLS];
        #pragma unroll
        for (int k = 0; k < KCLS; ++k) pk[k] = pb[(size_t)k * (HWD / 4)];
        const int4 lb = *(const int4*)(label + (size_t)b * HWD + s);
        const bool lab = is_lab[b] != 0;

        int pack = 0;
        #pragma unroll
        for (int j = 0; j < VPT; ++j) {
            float best = -1.f; int bi = 0;
            #pragma unroll
            for (int k = 0; k < KCLS; ++k) {
                float v = ((const float*)&pk[k])[j];
                if (v > best) { best = v; bi = k; }   // first-max == jnp.argmax
            }
            const int lj = ((const int*)&lb)[j];
            const bool m = (best > 0.8f) & (bi > 0) & ((bi == lj) | (!lab));
            if (m) {
                pack |= (4 | (bi - 1)) << (3 * j);
                atomicAdd(&lcnt[bi - 1], 1.0f);
            }
        }
        if (pack) wl[atomicAdd(&nwl, 1)] = pack | (t << 12);
    }
    __syncthreads();

    // ---- phase 2: lane = entry, wave w owns channels [16w, 16w+16) ----
    // One load instr = ≤64 entries × 16B inside ONE 4KB channel-plane span
    // (page-local), walking planes sequentially → DRAM row-buffer friendly.
    const int n = nwl;
    float sqacc[NC] = {0.f, 0.f, 0.f, 0.f};
    {
        const float4* fb = (const float4*)(feat + (size_t)b * CCH * HWD);
        const int plane = HWD / 4;
        const int sbase = chunk * (CHUNK / 4) - b * plane;
        const int c0 = w * 16;

        for (int base = 0; base < n; base += 64) {
            const bool act = (base + lane) < n;
            const int e = act ? wl[base + lane] : 0;    // e==0 → all voxels invalid
            const int grp = sbase + (e >> 12);

            #pragma unroll
            for (int half = 0; half < 2; ++half) {
                float4 f[8];
                #pragma unroll
                for (int u = 0; u < 8; ++u)
                    if (act) f[u] = fb[(size_t)(c0 + half * 8 + u) * plane + grp];
                #pragma unroll
                for (int u = 0; u < 8; ++u) {
                    const int c = c0 + half * 8 + u;
                    float sk[NC] = {0.f, 0.f, 0.f, 0.f};
                    #pragma unroll
                    for (int j = 0; j < VPT; ++j) {
                        const int bits = (e >> (3 * j)) & 7;
                        if (bits & 4) {                  // implies act
                            const float v = ((const float*)&f[u])[j];
                            const float v2 = v * v;
                            #pragma unroll
                            for (int k = 0; k < NC; ++k)
                                if ((bits & 3) == k) { sk[k] += v; sqacc[k] += v2; }
                        }
                    }
                    #pragma unroll
                    for (int o = 1; o < 64; o <<= 1) {
                        #pragma unroll
                        for (int k = 0; k < NC; ++k) sk[k] += __shfl_xor(sk[k], o);
                    }
                    if (lane < NC) lsum[lane][c] += sk[lane];   // disjoint c per wave
                }
            }
        }
    }
    #pragma unroll
    for (int o = 1; o < 64; o <<= 1) {
        #pragma unroll
        for (int k = 0; k < NC; ++k) sqacc[k] += __shfl_xor(sqacc[k], o);
    }
    if (lane < NC) atomicAdd(&lsq[lane], sqacc[lane]);
    __syncthreads();

    // ---- phase 3: flush block partials into one of NPART buckets ----
    float* dst = part + (size_t)(blockIdx.x & (NPART - 1)) * PARTSZ;
    const float vs = lsum[t >> 6][t & 63];
    if (vs != 0.f) atomicAdd(&dst[t], vs);
    if (t < NC) { float cv = lcnt[t]; if (cv != 0.f) atomicAdd(&dst[256 + t], cv); }
    if (t >= NC && t < 2 * NC) { float qv = lsq[t - NC]; if (qv != 0.f) atomicAdd(&dst[256 + t], qv); }
}

__global__ __launch_bounds__(256) void pm_pass2(
    const float* __restrict__ part, const float* __restrict__ proto,
    float* __restrict__ out)
{
    __shared__ float scnt[NC], ssq[NC], smu[NC * CCH], sred[4];
    __shared__ float s_intra;
    const int t = threadIdx.x;
    const int q = t >> 6;

    float s = 0.f;
    #pragma unroll
    for (int p = 0; p < NPART; ++p) s += part[p * PARTSZ + t];
    if (t < 2 * NC) {
        float a = 0.f;
        #pragma unroll
        for (int p = 0; p < NPART; ++p) a += part[p * PARTSZ + 256 + t];
        if (t < NC) scnt[t] = a; else ssq[t - NC] = a;
    }
    __syncthreads();

    const float cq = scnt[q];
    const float mean = s / fmaxf(cq, 1.f);
    const float pold = proto[t];                       // (4,64) row-major == t
    const float mu = (cq > 0.f) ? 0.9f * pold + 0.1f * mean : pold;
    out[3 + t] = mu;
    smu[t] = mu;

    // loss_intra numerator partial: -2*sums*mu + cnt*mu^2  (sumsq added at the end)
    float pi = -2.f * s * mu + cq * mu * mu;
    #pragma unroll
    for (int o = 1; o < 64; o <<= 1) pi += __shfl_xor(pi, o);
    if ((t & 63) == 0) sred[t >> 6] = pi;
    __syncthreads();

    if (t == 0) {
        float num = sred[0] + sred[1] + sred[2] + sred[3]
                  + ssq[0] + ssq[1] + ssq[2] + ssq[3];
        float nv = scnt[0] + scnt[1] + scnt[2] + scnt[3];
        s_intra = num / fmaxf(nv, 1.f);
    }
    __syncthreads();

    if (t < 64) {
        const int pi_[6] = {0, 0, 0, 1, 1, 2};
        const int pj_[6] = {1, 2, 3, 2, 3, 3};
        float acc = 0.f;
        #pragma unroll
        for (int e = 0; e < 6; ++e) {
            float d = smu[pi_[e] * 64 + t] - smu[pj_[e] * 64 + t];
            float d2 = d * d;
            #pragma unroll
            for (int o = 1; o < 64; o <<= 1) d2 += __shfl_xor(d2, o);
            float dist = sqrtf(d2 + 1e-12f);
            float vv = fmaxf(1.f - dist, 0.f);
            acc += vv * vv;
        }
        if (t == 0) {
            float li = acc / 6.f;                      // n_pairs = 6
            out[0] = s_intra + 0.1f * li;              // lambda_intra=1, lambda_inter=0.1
            out[1] = s_intra;
            out[2] = li;
        }
    }
}

extern "C" void kernel_launch(void* const* d_in, const int* in_sizes, int n_in,
                              void* d_out, int out_size, void* d_ws, size_t ws_size,
                              hipStream_t stream) {
    const float* feat         = (const float*)d_in[0];
    const float* pred         = (const float*)d_in[1];
    const int* label          = (const int*)d_in[2];
    const unsigned char* ilab = (const unsigned char*)d_in[3];   // jnp bool = 1 byte
    const float* proto        = (const float*)d_in[4];
    float* out                = (float*)d_out;
    float* part               = (float*)d_ws;

    hipLaunchKernelGGL(pm_zero, dim3(1), dim3(256), 0, stream, part);
    hipLaunchKernelGGL(pm_pass1, dim3(NCHUNKS), dim3(TPB), 0, stream,
                       feat, pred, label, ilab, part);
    hipLaunchKernelGGL(pm_pass2, dim3(1), dim3(256), 0, stream, part, proto, out);
}

// Round 6
// 110.123 us; speedup vs baseline: 1.5369x; 1.5369x over previous
//
#include <hip/hip_runtime.h>

#define HWD 884736   // 96*96*96
#define KCLS 5
#define CCH 64
#define NC 4

constexpr int PLANE4 = HWD / 4;      // float4 groups per channel plane (221184)
constexpr int GRP_B  = HWD / 4;      // voxel-groups per batch item
constexpr int NBLK   = 2 * GRP_B / 256;  // 1728 blocks of 256 groups
constexpr int NPART  = 16;
constexpr int PARTSZ = 272;          // 256 sums + 4 cnt @256 + 4 sq @260
constexpr int MASK_OFF_BYTES = 32768;

__global__ __launch_bounds__(256) void pm_zero(float* __restrict__ part) {
    const int n = NPART * PARTSZ;
    for (int i = threadIdx.x; i < n; i += 256) part[i] = 0.f;
}

// K1: compute per-voxel mask word (4 voxels x 3 bits: valid|class2) + class counts
__global__ __launch_bounds__(256) void pm_mask(
    const float* __restrict__ pred, const int* __restrict__ label,
    const unsigned char* __restrict__ is_lab,
    unsigned int* __restrict__ mask, float* __restrict__ part)
{
    __shared__ float lcnt[NC];
    const int t = threadIdx.x;
    if (t < NC) lcnt[t] = 0.f;
    __syncthreads();

    const int g = blockIdx.x * 256 + t;          // global float4-group id
    const int b = (blockIdx.x >= NBLK / 2);      // block never straddles batch
    const int gg = g - b * GRP_B;

    const float4* pb = (const float4*)(pred + (size_t)b * KCLS * HWD) + gg;
    float4 pk[KCLS];
    #pragma unroll
    for (int k = 0; k < KCLS; ++k) pk[k] = pb[(size_t)k * PLANE4];
    const int4 lb = ((const int4*)(label + (size_t)b * HWD))[gg];
    const bool lab = is_lab[b] != 0;

    unsigned int wd = 0;
    #pragma unroll
    for (int j = 0; j < 4; ++j) {
        float best = -1.f; int bi = 0;
        #pragma unroll
        for (int k = 0; k < KCLS; ++k) {
            float v = ((const float*)&pk[k])[j];
            if (v > best) { best = v; bi = k; }   // first-max == jnp.argmax
        }
        const int lj = ((const int*)&lb)[j];
        const bool m = (best > 0.8f) & (bi > 0) & ((bi == lj) | (!lab));
        if (m) {
            wd |= (4u | (unsigned)(bi - 1)) << (3 * j);
            atomicAdd(&lcnt[bi - 1], 1.f);
        }
    }
    mask[g] = wd;
    __syncthreads();
    if (t < NC) {
        float c = lcnt[t];
        if (c != 0.f) atomicAdd(&part[(size_t)(blockIdx.x & (NPART - 1)) * PARTSZ + 256 + t], c);
    }
}

// K2: dense coalesced sweep of feat; indicator-FMA accumulation per class
__global__ __launch_bounds__(256, 2) void pm_dense(
    const float* __restrict__ feat, const unsigned int* __restrict__ mask,
    float* __restrict__ part)
{
    __shared__ float4 red[64 * 65];   // [channel][lane] with +1 row pad
    const int t = threadIdx.x, w = t >> 6, l = t & 63;
    const int bi = blockIdx.x;
    const int b = (bi >= NBLK / 2);
    const int g0 = bi * 256 - b * GRP_B;          // group base within batch
    const float4* fb = (const float4*)feat + (size_t)b * CCH * PLANE4;
    const int c0 = w * 16;                         // wave owns channels [c0,c0+16)

    float4 acc[16];
    #pragma unroll
    for (int u = 0; u < 16; ++u) acc[u] = make_float4(0.f, 0.f, 0.f, 0.f);
    float sq[NC] = {0.f, 0.f, 0.f, 0.f};

    for (int i = 0; i < 4; ++i) {
        const int gl = i * 64 + l;                 // group within chunk
        const int gg = g0 + gl;                    // group within batch plane
        const unsigned int wm = mask[bi * 256 + gl];

        float4 fv[16];
        #pragma unroll
        for (int u = 0; u < 16; ++u)
            fv[u] = fb[(size_t)(c0 + u) * PLANE4 + gg];   // 16 coalesced 1KB loads

        float ind[4][NC];
        #pragma unroll
        for (int j = 0; j < 4; ++j) {
            const int bits = (wm >> (3 * j)) & 7;
            #pragma unroll
            for (int k = 0; k < NC; ++k)
                ind[j][k] = (bits == (4 | k)) ? 1.f : 0.f;
        }

        float vsq[4] = {0.f, 0.f, 0.f, 0.f};
        #pragma unroll
        for (int u = 0; u < 16; ++u) {
            #pragma unroll
            for (int j = 0; j < 4; ++j) {
                const float v = ((const float*)&fv[u])[j];
                vsq[j] = fmaf(v, v, vsq[j]);
                #pragma unroll
                for (int k = 0; k < NC; ++k)
                    ((float*)&acc[u])[k] = fmaf(ind[j][k], v, ((float*)&acc[u])[k]);
            }
        }
        #pragma unroll
        for (int j = 0; j < 4; ++j)
            #pragma unroll
            for (int k = 0; k < NC; ++k)
                sq[k] = fmaf(ind[j][k], vsq[j], sq[k]);
    }

    // stage per-lane partials: red[c][l] = float4 over classes
    #pragma unroll
    for (int u = 0; u < 16; ++u) red[(c0 + u) * 65 + l] = acc[u];

    // per-wave sumsq reduce + flush (independent of red[])
    #pragma unroll
    for (int k = 0; k < NC; ++k) {
        float v = sq[k];
        #pragma unroll
        for (int o = 1; o < 64; o <<= 1) v += __shfl_xor(v, o);
        sq[k] = v;
    }
    float* dst = part + (size_t)(bi & (NPART - 1)) * PARTSZ;
    if (l < NC) {
        float v = (l == 0) ? sq[0] : (l == 1) ? sq[1] : (l == 2) ? sq[2] : sq[3];
        if (v != 0.f) atomicAdd(&dst[260 + l], v);
    }
    __syncthreads();

    // block reduce over lanes: thread t -> (c = t>>2, k = t&3)
    const int c = t >> 2, k = t & 3;
    float s = 0.f;
    #pragma unroll 8
    for (int l2 = 0; l2 < 64; ++l2) s += ((const float*)&red[c * 65 + l2])[k];
    if (s != 0.f) atomicAdd(&dst[k * 64 + c], s);
}

__global__ __launch_bounds__(256) void pm_pass2(
    const float* __restrict__ part, const float* __restrict__ proto,
    float* __restrict__ out)
{
    __shared__ float scnt[NC], ssq[NC], smu[NC * CCH], sred[4];
    __shared__ float s_intra;
    const int t = threadIdx.x;
    const int q = t >> 6;

    float s = 0.f;
    #pragma unroll
    for (int p = 0; p < NPART; ++p) s += part[p * PARTSZ + t];
    if (t < 2 * NC) {
        float a = 0.f;
        #pragma unroll
        for (int p = 0; p < NPART; ++p) a += part[p * PARTSZ + 256 + t];
        if (t < NC) scnt[t] = a; else ssq[t - NC] = a;
    }
    __syncthreads();

    const float cq = scnt[q];
    const float mean = s / fmaxf(cq, 1.f);
    const float pold = proto[t];                       // (4,64) row-major == t
    const float mu = (cq > 0.f) ? 0.9f * pold + 0.1f * mean : pold;
    out[3 + t] = mu;
    smu[t] = mu;

    // loss_intra numerator partial: -2*sums*mu + cnt*mu^2  (sumsq added at the end)
    float pi = -2.f * s * mu + cq * mu * mu;
    #pragma unroll
    for (int o = 1; o < 64; o <<= 1) pi += __shfl_xor(pi, o);
    if ((t & 63) == 0) sred[t >> 6] = pi;
    __syncthreads();

    if (t == 0) {
        float num = sred[0] + sred[1] + sred[2] + sred[3]
                  + ssq[0] + ssq[1] + ssq[2] + ssq[3];
        float nv = scnt[0] + scnt[1] + scnt[2] + scnt[3];
        s_intra = num / fmaxf(nv, 1.f);
    }
    __syncthreads();

    if (t < 64) {
        const int pi_[6] = {0, 0, 0, 1, 1, 2};
        const int pj_[6] = {1, 2, 3, 2, 3, 3};
        float acc = 0.f;
        #pragma unroll
        for (int e = 0; e < 6; ++e) {
            float d = smu[pi_[e] * 64 + t] - smu[pj_[e] * 64 + t];
            float d2 = d * d;
            #pragma unroll
            for (int o = 1; o < 64; o <<= 1) d2 += __shfl_xor(d2, o);
            float dist = sqrtf(d2 + 1e-12f);
            float vv = fmaxf(1.f - dist, 0.f);
            acc += vv * vv;
        }
        if (t == 0) {
            float li = acc / 6.f;                      // n_pairs = 6
            out[0] = s_intra + 0.1f * li;              // lambda_intra=1, lambda_inter=0.1
            out[1] = s_intra;
            out[2] = li;
        }
    }
}

extern "C" void kernel_launch(void* const* d_in, const int* in_sizes, int n_in,
                              void* d_out, int out_size, void* d_ws, size_t ws_size,
                              hipStream_t stream) {
    const float* feat         = (const float*)d_in[0];
    const float* pred         = (const float*)d_in[1];
    const int* label          = (const int*)d_in[2];
    const unsigned char* ilab = (const unsigned char*)d_in[3];   // jnp bool = 1 byte
    const float* proto        = (const float*)d_in[4];
    float* out                = (float*)d_out;
    float* part               = (float*)d_ws;
    unsigned int* mask        = (unsigned int*)((char*)d_ws + MASK_OFF_BYTES);

    hipLaunchKernelGGL(pm_zero,  dim3(1),    dim3(256), 0, stream, part);
    hipLaunchKernelGGL(pm_mask,  dim3(NBLK), dim3(256), 0, stream,
                       pred, label, ilab, mask, part);
    hipLaunchKernelGGL(pm_dense, dim3(NBLK), dim3(256), 0, stream, feat, mask, part);
    hipLaunchKernelGGL(pm_pass2, dim3(1),    dim3(256), 0, stream, part, proto, out);
}

// Round 9
// 108.121 us; speedup vs baseline: 1.5654x; 1.0185x over previous
//
#include <hip/hip_runtime.h>

#define HWD 884736   // 96*96*96
#define KCLS 5
#define CCH 64
#define NC 4

constexpr int PLANE4 = HWD / 4;          // float4 groups per channel plane (221184)
constexpr int GRP_B  = HWD / 4;          // voxel-groups per batch item
constexpr int NBLK   = 2 * GRP_B / 256;  // 1728 blocks of 256 groups
constexpr int NPART  = 16;
constexpr int PARTSZ = 272;              // 256 sums + 4 cnt @256 + 4 sq @260

__global__ __launch_bounds__(256) void pm_zero(float* __restrict__ part) {
    const int n = NPART * PARTSZ;
    for (int i = threadIdx.x; i < n; i += 256) part[i] = 0.f;
}

// Fused: mask (pred/label -> 3b/voxel in LDS) + dense coalesced feat sweep
__global__ __launch_bounds__(256, 2) void pm_main(
    const float* __restrict__ feat, const float* __restrict__ pred,
    const int* __restrict__ label, const unsigned char* __restrict__ is_lab,
    float* __restrict__ part)
{
    __shared__ float4 red[64 * 65];      // [channel][lane], +1 float4 row pad
    __shared__ unsigned int smask[256];
    __shared__ float lcnt[NC];

    const int t = threadIdx.x, w = t >> 6, l = t & 63;
    const int bi = blockIdx.x;
    const int b = (bi >= NBLK / 2);                  // block never straddles batch
    const int g0 = bi * 256 - b * GRP_B;             // group base within batch plane

    if (t < NC) lcnt[t] = 0.f;
    __syncthreads();

    // ---- phase A: mask from pred/label (coalesced), one group per thread ----
    {
        const int gg = g0 + t;
        const float4* pb = (const float4*)(pred + (size_t)b * KCLS * HWD) + gg;
        float4 pk[KCLS];
        #pragma unroll
        for (int k = 0; k < KCLS; ++k) pk[k] = pb[(size_t)k * PLANE4];
        const int4 lb = ((const int4*)(label + (size_t)b * HWD))[gg];
        const bool lab = is_lab[b] != 0;

        unsigned int wd = 0;
        #pragma unroll
        for (int j = 0; j < 4; ++j) {
            float best = -1.f; int c = 0;
            #pragma unroll
            for (int k = 0; k < KCLS; ++k) {
                float v = ((const float*)&pk[k])[j];
                if (v > best) { best = v; c = k; }   // first-max == jnp.argmax
            }
            const int lj = ((const int*)&lb)[j];
            const bool m = (best > 0.8f) & (c > 0) & ((c == lj) | (!lab));
            if (m) {
                wd |= (4u | (unsigned)(c - 1)) << (3 * j);
                atomicAdd(&lcnt[c - 1], 1.f);
            }
        }
        smask[t] = wd;
    }
    __syncthreads();

    // ---- phase B: dense sweep; wave w owns channels [16w, 16w+16) ----
    const float4* fb = (const float4*)feat + (size_t)b * CCH * PLANE4;
    const int c0 = w * 16;

    float4 acc[16];
    #pragma unroll
    for (int u = 0; u < 16; ++u) acc[u] = make_float4(0.f, 0.f, 0.f, 0.f);
    float sq[NC] = {0.f, 0.f, 0.f, 0.f};

    for (int i = 0; i < 4; ++i) {
        const int gl = i * 64 + l;                   // group within block
        const int gg = g0 + gl;
        const unsigned int wm = smask[gl];

        float4 fv[16];
        #pragma unroll
        for (int u = 0; u < 16; ++u)
            fv[u] = fb[(size_t)(c0 + u) * PLANE4 + gg];   // 16 coalesced 1KB loads

        float ind[4][NC];
        #pragma unroll
        for (int j = 0; j < 4; ++j) {
            const int bits = (wm >> (3 * j)) & 7;
            #pragma unroll
            for (int k = 0; k < NC; ++k)
                ind[j][k] = (bits == (4 | k)) ? 1.f : 0.f;
        }

        float vsq[4] = {0.f, 0.f, 0.f, 0.f};
        #pragma unroll
        for (int u = 0; u < 16; ++u) {
            #pragma unroll
            for (int j = 0; j < 4; ++j) {
                const float v = ((const float*)&fv[u])[j];
                vsq[j] = fmaf(v, v, vsq[j]);
                #pragma unroll
                for (int k = 0; k < NC; ++k)
                    ((float*)&acc[u])[k] = fmaf(ind[j][k], v, ((float*)&acc[u])[k]);
            }
        }
        #pragma unroll
        for (int j = 0; j < 4; ++j)
            #pragma unroll
            for (int k = 0; k < NC; ++k)
                sq[k] = fmaf(ind[j][k], vsq[j], sq[k]);
    }

    // stage per-lane partials: red[c][l] = float4 over classes
    #pragma unroll
    for (int u = 0; u < 16; ++u) red[(c0 + u) * 65 + l] = acc[u];

    // per-wave sumsq butterfly + flush (independent of red[])
    #pragma unroll
    for (int k = 0; k < NC; ++k) {
        float v = sq[k];
        #pragma unroll
        for (int o = 1; o < 64; o <<= 1) v += __shfl_xor(v, o);
        sq[k] = v;
    }
    float* dst = part + (size_t)(bi & (NPART - 1)) * PARTSZ;
    if (l < NC) {
        float v = (l == 0) ? sq[0] : (l == 1) ? sq[1] : (l == 2) ? sq[2] : sq[3];
        if (v != 0.f) atomicAdd(&dst[260 + l], v);
    }
    if (t < NC) { float c = lcnt[t]; if (c != 0.f) atomicAdd(&dst[256 + t], c); }
    __syncthreads();

    // block reduce over lanes: thread t -> (c = t>>2, k = t&3); 2-way bank alias only
    const int c = t >> 2, k = t & 3;
    float s = 0.f;
    #pragma unroll 8
    for (int l2 = 0; l2 < 64; ++l2) s += ((const float*)&red[c * 65 + l2])[k];
    if (s != 0.f) atomicAdd(&dst[k * 64 + c], s);
}

__global__ __launch_bounds__(256) void pm_pass2(
    const float* __restrict__ part, const float* __restrict__ proto,
    float* __restrict__ out)
{
    __shared__ float scnt[NC], ssq[NC], smu[NC * CCH], sred[4];
    __shared__ float s_intra;
    const int t = threadIdx.x;
    const int q = t >> 6;

    float s = 0.f;
    #pragma unroll
    for (int p = 0; p < NPART; ++p) s += part[p * PARTSZ + t];
    if (t < 2 * NC) {
        float a = 0.f;
        #pragma unroll
        for (int p = 0; p < NPART; ++p) a += part[p * PARTSZ + 256 + t];
        if (t < NC) scnt[t] = a; else ssq[t - NC] = a;
    }
    __syncthreads();

    const float cq = scnt[q];
    const float mean = s / fmaxf(cq, 1.f);
    const float pold = proto[t];                       // (4,64) row-major == t
    const float mu = (cq > 0.f) ? 0.9f * pold + 0.1f * mean : pold;
    out[3 + t] = mu;
    smu[t] = mu;

    // loss_intra numerator partial: -2*sums*mu + cnt*mu^2  (sumsq added at the end)
    float pi = -2.f * s * mu + cq * mu * mu;
    #pragma unroll
    for (int o = 1; o < 64; o <<= 1) pi += __shfl_xor(pi, o);
    if ((t & 63) == 0) sred[t >> 6] = pi;
    __syncthreads();

    if (t == 0) {
        float num = sred[0] + sred[1] + sred[2] + sred[3]
                  + ssq[0] + ssq[1] + ssq[2] + ssq[3];
        float nv = scnt[0] + scnt[1] + scnt[2] + scnt[3];
        s_intra = num / fmaxf(nv, 1.f);
    }
    __syncthreads();

    if (t < 64) {
        const int pi_[6] = {0, 0, 0, 1, 1, 2};
        const int pj_[6] = {1, 2, 3, 2, 3, 3};
        float acc = 0.f;
        #pragma unroll
        for (int e = 0; e < 6; ++e) {
            float d = smu[pi_[e] * 64 + t] - smu[pj_[e] * 64 + t];
            float d2 = d * d;
            #pragma unroll
            for (int o = 1; o < 64; o <<= 1) d2 += __shfl_xor(d2, o);
            float dist = sqrtf(d2 + 1e-12f);
            float vv = fmaxf(1.f - dist, 0.f);
            acc += vv * vv;
        }
        if (t == 0) {
            float li = acc / 6.f;                      // n_pairs = 6
            out[0] = s_intra + 0.1f * li;              // lambda_intra=1, lambda_inter=0.1
            out[1] = s_intra;
            out[2] = li;
        }
    }
}

extern "C" void kernel_launch(void* const* d_in, const int* in_sizes, int n_in,
                              void* d_out, int out_size, void* d_ws, size_t ws_size,
                              hipStream_t stream) {
    const float* feat         = (const float*)d_in[0];
    const float* pred         = (const float*)d_in[1];
    const int* label          = (const int*)d_in[2];
    const unsigned char* ilab = (const unsigned char*)d_in[3];   // jnp bool = 1 byte
    const float* proto        = (const float*)d_in[4];
    float* out                = (float*)d_out;
    float* part               = (float*)d_ws;

    hipLaunchKernelGGL(pm_zero, dim3(1),    dim3(256), 0, stream, part);
    hipLaunchKernelGGL(pm_main, dim3(NBLK), dim3(256), 0, stream,
                       feat, pred, label, ilab, part);
    hipLaunchKernelGGL(pm_pass2, dim3(1),   dim3(256), 0, stream, part, proto, out);
}